// Round 10
// baseline (493.567 us; speedup 1.0000x reference)
//
#include <hip/hip_runtime.h>
#include <math.h>

#define N_NODES 100000
#define NFEAT 512
#define NHID 128
#define NCLASS 40

typedef unsigned int uint;
typedef unsigned short ushort;
typedef unsigned char uchar;
typedef short bf16x8 __attribute__((ext_vector_type(8)));
typedef float f32x4 __attribute__((ext_vector_type(4)));
typedef float f32x2 __attribute__((ext_vector_type(2)));

// f32 -> bf16 (RNE)
__device__ inline ushort bf16s(float a) {
    uint u = __float_as_uint(a);
    return (ushort)((u + 0x7fffu + ((u >> 16) & 1u)) >> 16);
}
__device__ inline uint bf16pack(float a, float b) {
    return (uint)bf16s(a) | ((uint)bf16s(b) << 16);
}
__device__ inline float bf16tof(ushort u) { return __uint_as_float(((uint)u) << 16); }
__device__ inline float bflo(uint u) { return __uint_as_float(u << 16); }
__device__ inline float bfhi(uint u) { return __uint_as_float(u & 0xffff0000u); }

// f32 -> fp8 e4m3 single byte (HW RNE)
__device__ inline uchar fp8byte(float v) {
    uint pk = __builtin_amdgcn_cvt_pk_fp8_f32(v, 0.f, 0u, false);
    return (uchar)(pk & 0xffu);
}

// ---------------------------------------------------------------------------
// weight prep (unchanged)
// ---------------------------------------------------------------------------
__global__ void prep_weights(const float* __restrict__ fc1_w, const float* __restrict__ conv_w,
                             ushort* __restrict__ wT1, ushort* __restrict__ wTc) {
    int idx = blockIdx.x * 256 + threadIdx.x;   // 65536 total
    {   int n = idx >> 9, k = idx & 511;
        wT1[idx] = bf16s(fc1_w[k * NHID + n]); }
    {   int L = idx >> 14, rem = idx & 16383;
        int n = rem >> 7, k = rem & 127;
        wTc[idx] = bf16s(conv_w[L * 16384 + k * NHID + n]); }
}

// ---------------------------------------------------------------------------
// packed edge metadata: emeta[e] = (cols[e], vals[e])
// ---------------------------------------------------------------------------
__global__ void prep_meta(const int* __restrict__ cols, const float* __restrict__ vals,
                          int2* __restrict__ emeta, int nE) {
    int e = blockIdx.x * 256 + threadIdx.x;
    if (e < nE) {
        int2 m; m.x = cols[e]; m.y = __float_as_int(vals[e]);
        emeta[e] = m;
    }
}

// ---------------------------------------------------------------------------
// row_ptr[i] = lower_bound(rows, i)
// ---------------------------------------------------------------------------
__global__ void rowptr_kernel(const int* __restrict__ rows, int* __restrict__ rowptr, int nE) {
    int i = blockIdx.x * blockDim.x + threadIdx.x;
    if (i > N_NODES) return;
    int lo = 0, hi = nE;
    while (lo < hi) { int mid = (lo + hi) >> 1; if (rows[mid] < i) lo = mid + 1; else hi = mid; }
    rowptr[i] = lo;
}

// ---------------------------------------------------------------------------
// fc1 MFMA, BM=64: h0 = relu(x @ W + b) -> h0b (bf16) + hf8 (fp8).
// A-stage reads clamped at N-1 for the tail block; stores guarded.
// ---------------------------------------------------------------------------
__global__ void __launch_bounds__(256) fc1_mfma(const float* __restrict__ x,
                                                const uint* __restrict__ wT1,
                                                const float* __restrict__ bias,
                                                ushort* __restrict__ h0b,
                                                uchar* __restrict__ hf8) {
    __shared__ ushort As[64][72];
    __shared__ ushort Bs[128][72];
    const int tid = threadIdx.x;
    const int lane = tid & 63;
    const int wave = tid >> 6;
    const int wr = wave >> 1, wc = wave & 1;
    const int r0 = blockIdx.x * 64;

    f32x4 acc[2][4] = {};

    for (int ks = 0; ks < NFEAT; ks += 64) {
        {   // stage A: 64 rows x 64 k, f32 -> bf16; thread: 16 consecutive k
            int row = tid >> 2, kq = tid & 3;
            int gr = r0 + row; if (gr > N_NODES - 1) gr = N_NODES - 1;
            const float* xp = x + (size_t)gr * NFEAT + ks + kq * 16;
            float4 v0 = *reinterpret_cast<const float4*>(xp);
            float4 v1 = *reinterpret_cast<const float4*>(xp + 4);
            float4 v2 = *reinterpret_cast<const float4*>(xp + 8);
            float4 v3 = *reinterpret_cast<const float4*>(xp + 12);
            uint4 p0, p1;
            p0.x = bf16pack(v0.x, v0.y); p0.y = bf16pack(v0.z, v0.w);
            p0.z = bf16pack(v1.x, v1.y); p0.w = bf16pack(v1.z, v1.w);
            p1.x = bf16pack(v2.x, v2.y); p1.y = bf16pack(v2.z, v2.w);
            p1.z = bf16pack(v3.x, v3.y); p1.w = bf16pack(v3.z, v3.w);
            *reinterpret_cast<uint4*>(&As[row][kq * 16]) = p0;
            *reinterpret_cast<uint4*>(&As[row][kq * 16 + 8]) = p1;
        }
        #pragma unroll
        for (int p = 0; p < 4; ++p) {   // stage B: 128 n x 64 k
            int idx = tid + p * 256;
            int n = idx >> 3, q = idx & 7;
            uint4 w4 = *reinterpret_cast<const uint4*>(wT1 + n * 256 + (ks >> 1) + q * 4);
            *reinterpret_cast<uint4*>(&Bs[n][q * 8]) = w4;
        }
        __syncthreads();
        #pragma unroll
        for (int ks2 = 0; ks2 < 64; ks2 += 32) {
            #pragma unroll
            for (int mr = 0; mr < 2; ++mr) {
                bf16x8 a = *reinterpret_cast<const bf16x8*>(
                    &As[wr * 32 + mr * 16 + (lane & 15)][ks2 + (lane >> 4) * 8]);
                #pragma unroll
                for (int j = 0; j < 4; ++j) {
                    bf16x8 b = *reinterpret_cast<const bf16x8*>(
                        &Bs[wc * 64 + j * 16 + (lane & 15)][ks2 + (lane >> 4) * 8]);
                    acc[mr][j] = __builtin_amdgcn_mfma_f32_16x16x32_bf16(a, b, acc[mr][j], 0, 0, 0);
                }
            }
        }
        __syncthreads();
    }

    const int cb = wc * 64 + (lane & 15);
    #pragma unroll
    for (int mr = 0; mr < 2; ++mr) {
        const int rloc = wr * 32 + mr * 16 + ((lane >> 4) << 2);
        #pragma unroll
        for (int j = 0; j < 4; ++j) {
            int col = cb + j * 16;
            float bj = bias[col];
            #pragma unroll
            for (int i = 0; i < 4; ++i) {
                int gr = r0 + rloc + i;
                if (gr < N_NODES) {
                    float v = fmaxf(acc[mr][j][i] + bj, 0.f);
                    h0b[(size_t)gr * NHID + col] = bf16s(v);
                    hf8[(size_t)gr * NHID + col] = fp8byte(v);
                }
            }
        }
    }
}

// ---------------------------------------------------------------------------
// SpMM + residual, lane-address-minimized:
// One wave per node; 8 OCTETS (8 lanes each) process edges 8t+oct.
// Per edge: 8 gather lanes (uint4 = 16B covers the 128B fp8 row) + one 8B
// packed-metadata load (8 lanes share the address) = 16 lane-addresses/edge
// (was 48). No shfl in the loop; 3-round octet reduce at the end.
// ---------------------------------------------------------------------------
__global__ void __launch_bounds__(256) spmm_kernel(
        const uint4* __restrict__ h8,       // fp8 gather table [node][8 uint4]
        const uint4* __restrict__ h0b4,     // bf16 residual   [node][16 uint4]
        const int* __restrict__ rowptr,
        const long long* __restrict__ emeta,// packed (col, val) per edge
        uint4* __restrict__ sb4) {          // bf16 out        [node][16 uint4]
    const int node = blockIdx.x * 4 + (threadIdx.x >> 6);
    const int lane = threadIdx.x & 63;
    const int oct = lane >> 3;        // edge slot within chunk
    const int l = lane & 7;           // 16B segment of the 128B row

    const int e0 = rowptr[node], e1 = rowptr[node + 1];

    f32x2 acc[8] = {};                // features l*16 + (0..15)

    #pragma unroll 2
    for (int base = e0; base < e1; base += 8) {
        const int m = e1 - base;
        int ee = (oct < m) ? (base + oct) : base;
        long long md = __builtin_nontemporal_load(emeta + ee);
        float v = (oct < m) ? __int_as_float((int)(md >> 32)) : 0.f;
        int   c = (int)md;
        uint4 hv = h8[(size_t)c * 8 + l];
        f32x2 vv = {v, v};
        acc[0] += vv * __builtin_amdgcn_cvt_pk_f32_fp8(hv.x, false);
        acc[1] += vv * __builtin_amdgcn_cvt_pk_f32_fp8(hv.x, true);
        acc[2] += vv * __builtin_amdgcn_cvt_pk_f32_fp8(hv.y, false);
        acc[3] += vv * __builtin_amdgcn_cvt_pk_f32_fp8(hv.y, true);
        acc[4] += vv * __builtin_amdgcn_cvt_pk_f32_fp8(hv.z, false);
        acc[5] += vv * __builtin_amdgcn_cvt_pk_f32_fp8(hv.z, true);
        acc[6] += vv * __builtin_amdgcn_cvt_pk_f32_fp8(hv.w, false);
        acc[7] += vv * __builtin_amdgcn_cvt_pk_f32_fp8(hv.w, true);
    }

    // reduce across the 8 octets (lane bits 3,4,5)
    #pragma unroll
    for (int d = 8; d <= 32; d <<= 1) {
        #pragma unroll
        for (int k = 0; k < 8; ++k) {
            acc[k].x += __shfl_xor(acc[k].x, d);
            acc[k].y += __shfl_xor(acc[k].y, d);
        }
    }

    if (oct == 0) {
        // lane l owns features [l*16, l*16+16) = uint4 slots 2l, 2l+1
        uint4 h0a = h0b4[(size_t)node * 16 + 2 * l];
        uint4 h0bv = h0b4[(size_t)node * 16 + 2 * l + 1];
        uint4 oa, ob;
        oa.x = bf16pack(0.9f * acc[0].x + 0.1f * bflo(h0a.x), 0.9f * acc[0].y + 0.1f * bfhi(h0a.x));
        oa.y = bf16pack(0.9f * acc[1].x + 0.1f * bflo(h0a.y), 0.9f * acc[1].y + 0.1f * bfhi(h0a.y));
        oa.z = bf16pack(0.9f * acc[2].x + 0.1f * bflo(h0a.z), 0.9f * acc[2].y + 0.1f * bfhi(h0a.z));
        oa.w = bf16pack(0.9f * acc[3].x + 0.1f * bflo(h0a.w), 0.9f * acc[3].y + 0.1f * bfhi(h0a.w));
        ob.x = bf16pack(0.9f * acc[4].x + 0.1f * bflo(h0bv.x), 0.9f * acc[4].y + 0.1f * bfhi(h0bv.x));
        ob.y = bf16pack(0.9f * acc[5].x + 0.1f * bflo(h0bv.y), 0.9f * acc[5].y + 0.1f * bfhi(h0bv.y));
        ob.z = bf16pack(0.9f * acc[6].x + 0.1f * bflo(h0bv.z), 0.9f * acc[6].y + 0.1f * bfhi(h0bv.z));
        ob.w = bf16pack(0.9f * acc[7].x + 0.1f * bflo(h0bv.w), 0.9f * acc[7].y + 0.1f * bfhi(h0bv.w));
        sb4[(size_t)node * 16 + 2 * l]     = oa;
        sb4[(size_t)node * 16 + 2 * l + 1] = ob;
    }
}

// ---------------------------------------------------------------------------
// conv layer MFMA, BM=64 (unchanged from R8)
// ---------------------------------------------------------------------------
__global__ void __launch_bounds__(256) layer_mfma(const uint* __restrict__ sb,
                                                  const uint* __restrict__ wTc,
                                                  float theta,
                                                  uchar* __restrict__ hf8,
                                                  float* __restrict__ fout) {
    __shared__ ushort As[64][136];
    __shared__ ushort Bs[128][136];
    const int tid = threadIdx.x;
    const int lane = tid & 63;
    const int wave = tid >> 6;
    const int wr = wave >> 1, wc = wave & 1;
    const int r0 = blockIdx.x * 64;

    #pragma unroll
    for (int p = 0; p < 4; ++p) {   // stage A: 64 rows x 128 k
        int idx = tid + p * 256;
        int row = idx >> 4, kq = idx & 15;
        uint4 v = *reinterpret_cast<const uint4*>(sb + (size_t)(r0 + row) * 64 + kq * 4);
        *reinterpret_cast<uint4*>(&As[row][kq * 8]) = v;
    }
    #pragma unroll
    for (int p = 0; p < 8; ++p) {   // stage B: 128 n x 128 k
        int idx = tid + p * 256;
        int n = idx >> 4, kq = idx & 15;
        uint4 v = *reinterpret_cast<const uint4*>(wTc + n * 64 + kq * 4);
        *reinterpret_cast<uint4*>(&Bs[n][kq * 8]) = v;
    }
    __syncthreads();

    f32x4 acc[2][4] = {};
    #pragma unroll
    for (int ks = 0; ks < NHID; ks += 32) {
        #pragma unroll
        for (int mr = 0; mr < 2; ++mr) {
            bf16x8 a = *reinterpret_cast<const bf16x8*>(&As[wr * 32 + mr * 16 + (lane & 15)][ks + (lane >> 4) * 8]);
            #pragma unroll
            for (int j = 0; j < 4; ++j) {
                bf16x8 b = *reinterpret_cast<const bf16x8*>(&Bs[wc * 64 + j * 16 + (lane & 15)][ks + (lane >> 4) * 8]);
                acc[mr][j] = __builtin_amdgcn_mfma_f32_16x16x32_bf16(a, b, acc[mr][j], 0, 0, 0);
            }
        }
    }

    const float om = 1.f - theta;
    #pragma unroll
    for (int mr = 0; mr < 2; ++mr) {
        const int rloc = wr * 32 + mr * 16 + ((lane >> 4) << 2);
        #pragma unroll
        for (int j = 0; j < 4; ++j) {
            int col = wc * 64 + j * 16 + (lane & 15);
            #pragma unroll
            for (int i = 0; i < 4; ++i) {
                int gr = r0 + rloc + i;
                if (gr < N_NODES) {
                    float s = bf16tof(As[rloc + i][col]);
                    float v = fmaxf(fmaf(theta, acc[mr][j][i], om * s), 0.f);
                    if (fout) fout[(size_t)gr * NHID + col] = v;
                    else      hf8[(size_t)gr * NHID + col] = fp8byte(v);
                }
            }
        }
    }
}

// ---------------------------------------------------------------------------
// final: logits = h @ fc2_w + b; out0 = log_softmax; out2 = [h, logits]
// ---------------------------------------------------------------------------
__global__ void final_kernel(const float* __restrict__ h, const float* __restrict__ w,
                             const float* __restrict__ b, float* __restrict__ out0,
                             float* __restrict__ out2) {
    __shared__ float hs[4][128];
    const int s = threadIdx.x >> 6;
    const int lane = threadIdx.x & 63;
    const int node = blockIdx.x * 4 + s;

    float h_lo = h[node * NHID + lane];
    float h_hi = h[node * NHID + 64 + lane];
    hs[s][lane] = h_lo;
    hs[s][64 + lane] = h_hi;
    __syncthreads();

    float logit = 0.f;
    if (lane < NCLASS) {
        logit = b[lane];
        #pragma unroll 8
        for (int k = 0; k < NHID; ++k)
            logit = fmaf(hs[s][k], w[k * NCLASS + lane], logit);
    }

    float mv = (lane < NCLASS) ? logit : -1e30f;
    #pragma unroll
    for (int m = 32; m; m >>= 1) mv = fmaxf(mv, __shfl_xor(mv, m));
    float ev = (lane < NCLASS) ? __expf(logit - mv) : 0.f;
    float sum = ev;
    #pragma unroll
    for (int m = 32; m; m >>= 1) sum += __shfl_xor(sum, m);
    float lse = mv + __logf(sum);

    if (lane < NCLASS) {
        out0[node * NCLASS + lane] = logit - lse;
        out2[node * 168 + 128 + lane] = logit;
    }
    out2[node * 168 + lane] = h_lo;
    out2[node * 168 + 64 + lane] = h_hi;
}

// ---------------------------------------------------------------------------
extern "C" void kernel_launch(void* const* d_in, const int* in_sizes, int n_in,
                              void* d_out, int out_size, void* d_ws, size_t ws_size,
                              hipStream_t stream) {
    const float* x      = (const float*)d_in[0];
    const int*   rows   = (const int*)  d_in[1];
    const int*   cols   = (const int*)  d_in[2];
    const float* vals   = (const float*)d_in[3];
    const float* fc1_w  = (const float*)d_in[4];
    const float* fc1_b  = (const float*)d_in[5];
    const float* conv_w = (const float*)d_in[6];
    const float* fc2_w  = (const float*)d_in[7];
    const float* fc2_b  = (const float*)d_in[8];
    float* out = (float*)d_out;

    const int nE = in_sizes[1];
    const size_t NH = (size_t)N_NODES * NHID;   // 12.8M elements
    const size_t PAD = 64 * NHID;               // tail padding for BM=64 A-staging

    // workspace layout
    char* p = (char*)d_ws;
    int*    rowptr = (int*)p;          p += 400128;            // 100001 ints, padded
    ushort* h0b    = (ushort*)p;       p += NH * 2;            // 25.6 MB bf16 residual
    ushort* sb     = (ushort*)p;       p += (NH + PAD) * 2;    // 25.6 MB bf16 support
    uchar*  hf8    = (uchar*)p;        p += NH;                // 12.8 MB fp8 gather table
    int2*   emeta  = (int2*)p;         p += (size_t)nE * 8;    // 12.8 MB packed edges
    ushort* wT1    = (ushort*)p;       p += 65536 * 2;         // 128 KB
    ushort* wTc    = (ushort*)p;       p += 65536 * 2;         // 128 KB

    // out regions
    float* out0 = out;                                  // [N,40]
    float* out1 = out + (size_t)N_NODES * NCLASS;       // [N,128] final h (f32)
    float* out2 = out1 + NH;                            // [N,168]

    prep_weights<<<256, 256, 0, stream>>>(fc1_w, conv_w, wT1, wTc);
    prep_meta<<<(nE + 255) / 256, 256, 0, stream>>>(cols, vals, emeta, nE);
    rowptr_kernel<<<(N_NODES + 1 + 255) / 256, 256, 0, stream>>>(rows, rowptr, nE);
    fc1_mfma<<<(N_NODES + 63) / 64, 256, 0, stream>>>(x, (const uint*)wT1, fc1_b, h0b, hf8);

    for (int i = 0; i < 4; ++i) {
        float theta = logf(0.5f / (float)(i + 1) + 1.0f);
        spmm_kernel<<<N_NODES / 4, 256, 0, stream>>>(
            (const uint4*)hf8, (const uint4*)h0b, rowptr, (const long long*)emeta, (uint4*)sb);
        layer_mfma<<<(N_NODES + 63) / 64, 256, 0, stream>>>(
            (const uint*)sb, (const uint*)(wTc + (size_t)i * 16384), theta,
            hf8, (i == 3) ? out1 : nullptr);
    }

    final_kernel<<<N_NODES / 4, 256, 0, stream>>>(out1, fc2_w, fc2_b, out0, out2);
}

// Round 11
// 464.087 us; speedup vs baseline: 1.0635x; 1.0635x over previous
//
#include <hip/hip_runtime.h>
#include <math.h>

#define N_NODES 100000
#define NFEAT 512
#define NHID 128
#define NCLASS 40

typedef unsigned int uint;
typedef unsigned short ushort;
typedef unsigned char uchar;
typedef short bf16x8 __attribute__((ext_vector_type(8)));
typedef float f32x4 __attribute__((ext_vector_type(4)));
typedef float f32x2 __attribute__((ext_vector_type(2)));

// f32 -> bf16 (RNE)
__device__ inline ushort bf16s(float a) {
    uint u = __float_as_uint(a);
    return (ushort)((u + 0x7fffu + ((u >> 16) & 1u)) >> 16);
}
__device__ inline uint bf16pack(float a, float b) {
    return (uint)bf16s(a) | ((uint)bf16s(b) << 16);
}
__device__ inline float bf16tof(ushort u) { return __uint_as_float(((uint)u) << 16); }
__device__ inline float bflo(uint u) { return __uint_as_float(u << 16); }
__device__ inline float bfhi(uint u) { return __uint_as_float(u & 0xffff0000u); }

// f32 -> fp8 e4m3 single byte (HW RNE)
__device__ inline uchar fp8byte(float v) {
    uint pk = __builtin_amdgcn_cvt_pk_fp8_f32(v, 0.f, 0u, false);
    return (uchar)(pk & 0xffu);
}

// ---------------------------------------------------------------------------
// weight prep: wT1[n][k] = bf16(fc1_w[k][n])   (128 x 512)
//              wTc[L][n][k] = bf16(conv_w[L][k][n])  (4 x 128 x 128)
// ---------------------------------------------------------------------------
__global__ void prep_weights(const float* __restrict__ fc1_w, const float* __restrict__ conv_w,
                             ushort* __restrict__ wT1, ushort* __restrict__ wTc) {
    int idx = blockIdx.x * 256 + threadIdx.x;   // 65536 total
    {   int n = idx >> 9, k = idx & 511;
        wT1[idx] = bf16s(fc1_w[k * NHID + n]); }
    {   int L = idx >> 14, rem = idx & 16383;
        int n = rem >> 7, k = rem & 127;
        wTc[idx] = bf16s(conv_w[L * 16384 + k * NHID + n]); }
}

// ---------------------------------------------------------------------------
// row_ptr[i] = lower_bound(rows, i)
// ---------------------------------------------------------------------------
__global__ void rowptr_kernel(const int* __restrict__ rows, int* __restrict__ rowptr, int nE) {
    int i = blockIdx.x * blockDim.x + threadIdx.x;
    if (i > N_NODES) return;
    int lo = 0, hi = nE;
    while (lo < hi) { int mid = (lo + hi) >> 1; if (rows[mid] < i) lo = mid + 1; else hi = mid; }
    rowptr[i] = lo;
}

// ---------------------------------------------------------------------------
// fc1 MFMA, BM=64: h0 = relu(x @ W + b) -> h0b (bf16) + hf8 (fp8).
// A-stage reads clamped at N-1 for the tail block; stores guarded.
// ---------------------------------------------------------------------------
__global__ void __launch_bounds__(256) fc1_mfma(const float* __restrict__ x,
                                                const uint* __restrict__ wT1,
                                                const float* __restrict__ bias,
                                                ushort* __restrict__ h0b,
                                                uchar* __restrict__ hf8) {
    __shared__ ushort As[64][72];
    __shared__ ushort Bs[128][72];
    const int tid = threadIdx.x;
    const int lane = tid & 63;
    const int wave = tid >> 6;
    const int wr = wave >> 1, wc = wave & 1;
    const int r0 = blockIdx.x * 64;

    f32x4 acc[2][4] = {};

    for (int ks = 0; ks < NFEAT; ks += 64) {
        {   // stage A: 64 rows x 64 k, f32 -> bf16; thread: 16 consecutive k
            int row = tid >> 2, kq = tid & 3;
            int gr = r0 + row; if (gr > N_NODES - 1) gr = N_NODES - 1;
            const float* xp = x + (size_t)gr * NFEAT + ks + kq * 16;
            float4 v0 = *reinterpret_cast<const float4*>(xp);
            float4 v1 = *reinterpret_cast<const float4*>(xp + 4);
            float4 v2 = *reinterpret_cast<const float4*>(xp + 8);
            float4 v3 = *reinterpret_cast<const float4*>(xp + 12);
            uint4 p0, p1;
            p0.x = bf16pack(v0.x, v0.y); p0.y = bf16pack(v0.z, v0.w);
            p0.z = bf16pack(v1.x, v1.y); p0.w = bf16pack(v1.z, v1.w);
            p1.x = bf16pack(v2.x, v2.y); p1.y = bf16pack(v2.z, v2.w);
            p1.z = bf16pack(v3.x, v3.y); p1.w = bf16pack(v3.z, v3.w);
            *reinterpret_cast<uint4*>(&As[row][kq * 16]) = p0;
            *reinterpret_cast<uint4*>(&As[row][kq * 16 + 8]) = p1;
        }
        #pragma unroll
        for (int p = 0; p < 4; ++p) {   // stage B: 128 n x 64 k
            int idx = tid + p * 256;
            int n = idx >> 3, q = idx & 7;
            uint4 w4 = *reinterpret_cast<const uint4*>(wT1 + n * 256 + (ks >> 1) + q * 4);
            *reinterpret_cast<uint4*>(&Bs[n][q * 8]) = w4;
        }
        __syncthreads();
        #pragma unroll
        for (int ks2 = 0; ks2 < 64; ks2 += 32) {
            #pragma unroll
            for (int mr = 0; mr < 2; ++mr) {
                bf16x8 a = *reinterpret_cast<const bf16x8*>(
                    &As[wr * 32 + mr * 16 + (lane & 15)][ks2 + (lane >> 4) * 8]);
                #pragma unroll
                for (int j = 0; j < 4; ++j) {
                    bf16x8 b = *reinterpret_cast<const bf16x8*>(
                        &Bs[wc * 64 + j * 16 + (lane & 15)][ks2 + (lane >> 4) * 8]);
                    acc[mr][j] = __builtin_amdgcn_mfma_f32_16x16x32_bf16(a, b, acc[mr][j], 0, 0, 0);
                }
            }
        }
        __syncthreads();
    }

    const int cb = wc * 64 + (lane & 15);
    #pragma unroll
    for (int mr = 0; mr < 2; ++mr) {
        const int rloc = wr * 32 + mr * 16 + ((lane >> 4) << 2);
        #pragma unroll
        for (int j = 0; j < 4; ++j) {
            int col = cb + j * 16;
            float bj = bias[col];
            #pragma unroll
            for (int i = 0; i < 4; ++i) {
                int gr = r0 + rloc + i;
                if (gr < N_NODES) {
                    float v = fmaxf(acc[mr][j][i] + bj, 0.f);
                    h0b[(size_t)gr * NHID + col] = bf16s(v);
                    hf8[(size_t)gr * NHID + col] = fp8byte(v);
                }
            }
        }
    }
}

// ---------------------------------------------------------------------------
// SpMM + residual, shfl-free (exact R8 structure — proven best):
//   sb[n,:] = bf16(0.9 * sum_e vals[e]*fp8(h)[cols[e],:] + 0.1*h0b[n,:])
// One wave per node. Quarter q (16 lanes) walks edges e0+q, e0+q+4, ...
// All 16 lanes of a quarter load the SAME cols[e]/vals[e] address (hardware
// broadcasts; one line request). Gather row = 128B fp8 (uint2/lane).
// ---------------------------------------------------------------------------
__global__ void __launch_bounds__(256) spmm_kernel(
        const uint2* __restrict__ h8,       // fp8 gather table [node][16 uint2]
        const uint4* __restrict__ h0b4,     // bf16 residual   [node][16 uint4]
        const int* __restrict__ rowptr,
        const int* __restrict__ cols,
        const float* __restrict__ vals,
        uint4* __restrict__ sb4) {          // bf16 out        [node][16 uint4]
    const int node = blockIdx.x * 4 + (threadIdx.x >> 6);
    const int lane = threadIdx.x & 63;
    const int q = lane >> 4;          // edge-parity quarter
    const int l = lane & 15;          // feature octet: features 8l..8l+7

    const int e0 = rowptr[node], e1 = rowptr[node + 1];

    f32x2 a0 = {0.f, 0.f}, a1 = {0.f, 0.f}, a2 = {0.f, 0.f}, a3 = {0.f, 0.f};
    #pragma unroll 4
    for (int e = e0 + q; e < e1; e += 4) {
        int   c = cols[e];            // same addr across the 16-lane quarter
        float v = vals[e];
        uint2 hv = h8[(size_t)c * 16 + l];
        f32x2 p0 = __builtin_amdgcn_cvt_pk_f32_fp8(hv.x, false);
        f32x2 p1 = __builtin_amdgcn_cvt_pk_f32_fp8(hv.x, true);
        f32x2 p2 = __builtin_amdgcn_cvt_pk_f32_fp8(hv.y, false);
        f32x2 p3 = __builtin_amdgcn_cvt_pk_f32_fp8(hv.y, true);
        f32x2 vv = {v, v};
        a0 += vv * p0;
        a1 += vv * p1;
        a2 += vv * p2;
        a3 += vv * p3;
    }

    // combine the four quarters (lane bits 4,5)
    #pragma unroll
    for (int d = 16; d <= 32; d <<= 1) {
        a0.x += __shfl_xor(a0.x, d); a0.y += __shfl_xor(a0.y, d);
        a1.x += __shfl_xor(a1.x, d); a1.y += __shfl_xor(a1.y, d);
        a2.x += __shfl_xor(a2.x, d); a2.y += __shfl_xor(a2.y, d);
        a3.x += __shfl_xor(a3.x, d); a3.y += __shfl_xor(a3.y, d);
    }

    if (q == 0) {
        uint4 h0v = h0b4[(size_t)node * 16 + l];
        uint4 o;
        o.x = bf16pack(0.9f * a0.x + 0.1f * bflo(h0v.x), 0.9f * a0.y + 0.1f * bfhi(h0v.x));
        o.y = bf16pack(0.9f * a1.x + 0.1f * bflo(h0v.y), 0.9f * a1.y + 0.1f * bfhi(h0v.y));
        o.z = bf16pack(0.9f * a2.x + 0.1f * bflo(h0v.z), 0.9f * a2.y + 0.1f * bfhi(h0v.z));
        o.w = bf16pack(0.9f * a3.x + 0.1f * bflo(h0v.w), 0.9f * a3.y + 0.1f * bfhi(h0v.w));
        sb4[(size_t)node * 16 + l] = o;
    }
}

// ---------------------------------------------------------------------------
// conv layer MFMA, BM=64, two-half B staging (LDS 35.8 KB -> 4 blocks/CU):
// out = relu(theta*(S @ W) + (1-theta)*S).
// Layers 0..2 write ONLY the fp8 gather copy; layer 3 writes f32 h.
// ---------------------------------------------------------------------------
__global__ void __launch_bounds__(256) layer_mfma(const uint* __restrict__ sb,
                                                  const uint* __restrict__ wTc,
                                                  float theta,
                                                  uchar* __restrict__ hf8,
                                                  float* __restrict__ fout) {
    __shared__ ushort As[64][136];
    __shared__ ushort Bs[128][72];
    const int tid = threadIdx.x;
    const int lane = tid & 63;
    const int wave = tid >> 6;
    const int wr = wave >> 1, wc = wave & 1;
    const int r0 = blockIdx.x * 64;

    // stage B half 0 (k 0..63) first so it overlaps A staging
    #pragma unroll
    for (int p = 0; p < 4; ++p) {
        int idx = tid + p * 256;            // 0..1023
        int n = idx >> 3, q = idx & 7;
        uint4 v = *reinterpret_cast<const uint4*>(wTc + n * 64 + q * 4);
        *reinterpret_cast<uint4*>(&Bs[n][q * 8]) = v;
    }
    #pragma unroll
    for (int p = 0; p < 4; ++p) {   // stage A: 64 rows x 128 k
        int idx = tid + p * 256;
        int row = idx >> 4, kq = idx & 15;
        uint4 v = *reinterpret_cast<const uint4*>(sb + (size_t)(r0 + row) * 64 + kq * 4);
        *reinterpret_cast<uint4*>(&As[row][kq * 8]) = v;
    }
    __syncthreads();

    f32x4 acc[2][4] = {};
    #pragma unroll
    for (int halfk = 0; halfk < 2; ++halfk) {
        if (halfk) {
            __syncthreads();
            #pragma unroll
            for (int p = 0; p < 4; ++p) {   // stage B half 1 (k 64..127)
                int idx = tid + p * 256;
                int n = idx >> 3, q = idx & 7;
                uint4 v = *reinterpret_cast<const uint4*>(wTc + n * 64 + 32 + q * 4);
                *reinterpret_cast<uint4*>(&Bs[n][q * 8]) = v;
            }
            __syncthreads();
        }
        #pragma unroll
        for (int ks2 = 0; ks2 < 64; ks2 += 32) {
            #pragma unroll
            for (int mr = 0; mr < 2; ++mr) {
                bf16x8 a = *reinterpret_cast<const bf16x8*>(
                    &As[wr * 32 + mr * 16 + (lane & 15)][halfk * 64 + ks2 + (lane >> 4) * 8]);
                #pragma unroll
                for (int j = 0; j < 4; ++j) {
                    bf16x8 b = *reinterpret_cast<const bf16x8*>(
                        &Bs[wc * 64 + j * 16 + (lane & 15)][ks2 + (lane >> 4) * 8]);
                    acc[mr][j] = __builtin_amdgcn_mfma_f32_16x16x32_bf16(a, b, acc[mr][j], 0, 0, 0);
                }
            }
        }
    }

    const float om = 1.f - theta;
    #pragma unroll
    for (int mr = 0; mr < 2; ++mr) {
        const int rloc = wr * 32 + mr * 16 + ((lane >> 4) << 2);
        #pragma unroll
        for (int j = 0; j < 4; ++j) {
            int col = wc * 64 + j * 16 + (lane & 15);
            #pragma unroll
            for (int i = 0; i < 4; ++i) {
                int gr = r0 + rloc + i;
                if (gr < N_NODES) {
                    float s = bf16tof(As[rloc + i][col]);
                    float v = fmaxf(fmaf(theta, acc[mr][j][i], om * s), 0.f);
                    if (fout) fout[(size_t)gr * NHID + col] = v;
                    else      hf8[(size_t)gr * NHID + col] = fp8byte(v);
                }
            }
        }
    }
}

// ---------------------------------------------------------------------------
// final: logits = h @ fc2_w + b; out0 = log_softmax; out2 = [h, logits]
// ---------------------------------------------------------------------------
__global__ void final_kernel(const float* __restrict__ h, const float* __restrict__ w,
                             const float* __restrict__ b, float* __restrict__ out0,
                             float* __restrict__ out2) {
    __shared__ float hs[4][128];
    const int s = threadIdx.x >> 6;
    const int lane = threadIdx.x & 63;
    const int node = blockIdx.x * 4 + s;

    float h_lo = h[node * NHID + lane];
    float h_hi = h[node * NHID + 64 + lane];
    hs[s][lane] = h_lo;
    hs[s][64 + lane] = h_hi;
    __syncthreads();

    float logit = 0.f;
    if (lane < NCLASS) {
        logit = b[lane];
        #pragma unroll 8
        for (int k = 0; k < NHID; ++k)
            logit = fmaf(hs[s][k], w[k * NCLASS + lane], logit);
    }

    float mv = (lane < NCLASS) ? logit : -1e30f;
    #pragma unroll
    for (int m = 32; m; m >>= 1) mv = fmaxf(mv, __shfl_xor(mv, m));
    float ev = (lane < NCLASS) ? __expf(logit - mv) : 0.f;
    float sum = ev;
    #pragma unroll
    for (int m = 32; m; m >>= 1) sum += __shfl_xor(sum, m);
    float lse = mv + __logf(sum);

    if (lane < NCLASS) {
        out0[node * NCLASS + lane] = logit - lse;
        out2[node * 168 + 128 + lane] = logit;
    }
    out2[node * 168 + lane] = h_lo;
    out2[node * 168 + 64 + lane] = h_hi;
}

// ---------------------------------------------------------------------------
extern "C" void kernel_launch(void* const* d_in, const int* in_sizes, int n_in,
                              void* d_out, int out_size, void* d_ws, size_t ws_size,
                              hipStream_t stream) {
    const float* x      = (const float*)d_in[0];
    const int*   rows   = (const int*)  d_in[1];
    const int*   cols   = (const int*)  d_in[2];
    const float* vals   = (const float*)d_in[3];
    const float* fc1_w  = (const float*)d_in[4];
    const float* fc1_b  = (const float*)d_in[5];
    const float* conv_w = (const float*)d_in[6];
    const float* fc2_w  = (const float*)d_in[7];
    const float* fc2_b  = (const float*)d_in[8];
    float* out = (float*)d_out;

    const int nE = in_sizes[1];
    const size_t NH = (size_t)N_NODES * NHID;   // 12.8M elements
    const size_t PAD = 64 * NHID;               // tail padding for BM=64 A-staging

    // workspace layout
    char* p = (char*)d_ws;
    int*    rowptr = (int*)p;          p += 400128;            // 100001 ints, padded
    ushort* h0b    = (ushort*)p;       p += NH * 2;            // 25.6 MB bf16 residual
    ushort* sb     = (ushort*)p;       p += (NH + PAD) * 2;    // 25.6 MB bf16 support
    uchar*  hf8    = (uchar*)p;        p += NH;                // 12.8 MB fp8 gather table
    ushort* wT1    = (ushort*)p;       p += 65536 * 2;         // 128 KB
    ushort* wTc    = (ushort*)p;       p += 65536 * 2;         // 128 KB

    // out regions
    float* out0 = out;                                  // [N,40]
    float* out1 = out + (size_t)N_NODES * NCLASS;       // [N,128] final h (f32)
    float* out2 = out1 + NH;                            // [N,168]

    prep_weights<<<256, 256, 0, stream>>>(fc1_w, conv_w, wT1, wTc);
    rowptr_kernel<<<(N_NODES + 1 + 255) / 256, 256, 0, stream>>>(rows, rowptr, nE);
    fc1_mfma<<<(N_NODES + 63) / 64, 256, 0, stream>>>(x, (const uint*)wT1, fc1_b, h0b, hf8);

    for (int i = 0; i < 4; ++i) {
        float theta = logf(0.5f / (float)(i + 1) + 1.0f);
        spmm_kernel<<<N_NODES / 4, 256, 0, stream>>>(
            (const uint2*)hf8, (const uint4*)h0b, rowptr, cols, vals, (uint4*)sb);
        layer_mfma<<<(N_NODES + 63) / 64, 256, 0, stream>>>(
            (const uint*)sb, (const uint*)(wTc + (size_t)i * 16384), theta,
            hf8, (i == 3) ? out1 : nullptr);
    }

    final_kernel<<<N_NODES / 4, 256, 0, stream>>>(out1, fc2_w, fc2_b, out0, out2);
}